// Round 1
// baseline (475.792 us; speedup 1.0000x reference)
//
#include <hip/hip_runtime.h>
#include <math.h>

// Problem constants (B, Cin, Cmid, H, W) = (2, 256, 128, 112, 112), R=3
constexpr int B    = 2;
constexpr int CIN  = 256;
constexpr int CMID = 128;
constexpr int H    = 112;
constexpr int W    = 112;
constexpr int HW   = H * W;        // 12544
constexpr int RAD  = 3;
constexpr int KS   = 7;
constexpr int DD   = 49;

// ---------------------------------------------------------------------------
// Kernel 1: q = l2norm(Wq @ phi_cur), k = l2norm(Wk @ phi_rnd)
// Output layout: pixel-major  qk[(b*HW + p)*CMID + c]   (contiguous channels)
// grid (HW/64, B, 2), block 256.  Wave w handles channels [32w, 32w+32) for
// 64 pixels (lane = pixel).  phi loads coalesced; W loads wave-uniform
// (scalar pipe); cross-wave norm reduction via LDS.
// ---------------------------------------------------------------------------
__global__ __launch_bounds__(256) void proj_kernel(
    const float* __restrict__ phi_cur, const float* __restrict__ phi_rnd,
    const float* __restrict__ Wq, const float* __restrict__ Wk,
    float* __restrict__ q_ws, float* __restrict__ k_ws)
{
    const int lane = threadIdx.x & 63;
    const int wv   = threadIdx.x >> 6;            // 0..3 channel group
    const int px   = blockIdx.x * 64 + lane;      // pixel in [0,HW)
    const int b    = blockIdx.y;
    const int t    = blockIdx.z;                  // 0 -> q, 1 -> k

    const float* __restrict__ phi = t ? phi_rnd : phi_cur;
    const float* __restrict__ Wm  = t ? Wk : Wq;
    float* __restrict__ out       = t ? k_ws : q_ws;

    const float* pb = phi + (size_t)b * CIN * HW + px;

    float acc[32];
#pragma unroll
    for (int j = 0; j < 32; ++j) acc[j] = 0.f;

    for (int c0 = 0; c0 < CIN; c0 += 32) {
        float pv[32];
#pragma unroll
        for (int cc = 0; cc < 32; ++cc)
            pv[cc] = pb[(size_t)(c0 + cc) * HW];
#pragma unroll
        for (int j = 0; j < 32; ++j) {
            const float* wr = Wm + (wv * 32 + j) * CIN + c0;  // wave-uniform
#pragma unroll
            for (int cc = 0; cc < 32; ++cc)
                acc[j] = fmaf(wr[cc], pv[cc], acc[j]);
        }
    }

    // L2 norm across all 128 channels of this pixel (4 wave-partials)
    float ss = 0.f;
#pragma unroll
    for (int j = 0; j < 32; ++j) ss = fmaf(acc[j], acc[j], ss);

    __shared__ float red[4][64];
    red[wv][lane] = ss;
    __syncthreads();
    const float tot = red[0][lane] + red[1][lane] + red[2][lane] + red[3][lane];
    const float inv = 1.f / fmaxf(sqrtf(tot), 1e-12f);

    float* op = out + ((size_t)(b * HW + px)) * CMID + wv * 32;
#pragma unroll
    for (int j = 0; j < 32; j += 4) {
        float4 v = make_float4(acc[j] * inv, acc[j + 1] * inv,
                               acc[j + 2] * inv, acc[j + 3] * inv);
        *(float4*)(op + j) = v;
    }
}

// ---------------------------------------------------------------------------
// Kernel 2: fused correlation + Wv matmul + geometry + softmax + moments.
// One wave per pixel, lane d = patch offset (d<49), dy=d/7-3, dx=d%7-3.
// OOB patches are ZERO (corr=0, Pr=0 -> dP=P_cur) but stay in the softmax,
// matching conv_general_dilated_patches zero padding.
// conf = max_d w_d = 1/Z  (Z = sum exp(l - lmax)).
// grid (B*HW/4), block 256.
// ---------------------------------------------------------------------------
__global__ __launch_bounds__(256) void corr_kernel(
    const float* __restrict__ q_ws, const float* __restrict__ k_ws,
    const float* __restrict__ P_cur, const float* __restrict__ P_rnd,
    const float* __restrict__ Wvm, const float* __restrict__ bv,
    const float* __restrict__ gamma_p, float* __restrict__ out)
{
    __shared__ float wv_lds[DD * DD];   // 2401 floats; row stride 49 is
    __shared__ float bv_lds[DD];        // coprime with 32 banks -> no conflict
    __shared__ float qs[4][CMID];
    __shared__ float cs[4][64];

    for (int i = threadIdx.x; i < DD * DD; i += 256) wv_lds[i] = Wvm[i];
    if (threadIdx.x < DD) bv_lds[threadIdx.x] = bv[threadIdx.x];

    const int lane = threadIdx.x & 63;
    const int wv   = threadIdx.x >> 6;
    const int pg   = blockIdx.x * 4 + wv;   // pixel among B*HW
    const int b    = pg / HW;
    const int p    = pg % HW;
    const int h    = p / W;
    const int w    = p % W;
    const float gamma = gamma_p[0];

    // stage this pixel's q vector (128 floats) into LDS
    const float* qp = q_ws + (size_t)pg * CMID;
    qs[wv][lane]      = qp[lane];
    qs[wv][lane + 64] = qp[lane + 64];
    __syncthreads();

    const int dy = lane / KS - RAD;
    const int dx = lane % KS - RAD;
    const int hn = h + dy, wn = w + dx;
    const bool valid = (lane < DD);
    const bool inb = valid && (hn >= 0) && (hn < H) && (wn >= 0) && (wn < W);

    // correlation: dot(q, k[neighbor]) over 128 channels
    float corr = 0.f;
    if (inb) {
        const float* kp = k_ws + ((size_t)b * HW + hn * W + wn) * CMID;
#pragma unroll 8
        for (int c = 0; c < CMID; c += 4) {
            float4 kq = *(const float4*)(kp + c);
            corr = fmaf(qs[wv][c],     kq.x, corr);
            corr = fmaf(qs[wv][c + 1], kq.y, corr);
            corr = fmaf(qs[wv][c + 2], kq.z, corr);
            corr = fmaf(qs[wv][c + 3], kq.w, corr);
        }
    }
    if (valid) cs[wv][lane] = corr;
    __syncthreads();

    // geometry
    float dpx, dpy, dpz;
    {
        const float* pc = P_cur + (size_t)b * 3 * HW + p;
        const float cx = pc[0], cy = pc[HW], cz = pc[2 * HW];
        float rx = 0.f, ry = 0.f, rz = 0.f;
        if (inb) {
            const float* pr = P_rnd + (size_t)b * 3 * HW + hn * W + wn;
            rx = pr[0]; ry = pr[HW]; rz = pr[2 * HW];
        }
        dpx = cx - rx; dpy = cy - ry; dpz = cz - rz;
    }
    const float dist = sqrtf(fmaxf(dpx * dpx + dpy * dpy + dpz * dpz, 1e-12f));

    // logits: Wv @ corr + bv + gamma * (-dist - 0.5*|dz|)
    float logit = -INFINITY;
    if (valid) {
        float v = bv_lds[lane];
        const float* wrow = wv_lds + lane * DD;
        const float* crow = cs[wv];
#pragma unroll 7
        for (int dd = 0; dd < DD; ++dd)
            v = fmaf(wrow[dd], crow[dd], v);
        logit = v + gamma * (-dist - 0.5f * fabsf(dpz));
    }

    // in-wave softmax over 49 active lanes
    float lmax = logit;
#pragma unroll
    for (int off = 32; off; off >>= 1)
        lmax = fmaxf(lmax, __shfl_xor(lmax, off, 64));
    const float e = valid ? __expf(logit - lmax) : 0.f;
    float Z = e;
#pragma unroll
    for (int off = 32; off; off >>= 1)
        Z += __shfl_xor(Z, off, 64);
    const float wgt = e / Z;

    float dus = wgt * (float)dx;
    float dvs = wgt * (float)dy;
#pragma unroll
    for (int off = 32; off; off >>= 1) {
        dus += __shfl_xor(dus, off, 64);
        dvs += __shfl_xor(dvs, off, 64);
    }

    if (lane == 0) {
        out[pg]                      = dus;        // du
        out[(size_t)B * HW + pg]     = dvs;        // dv
        out[2 * (size_t)B * HW + pg] = 1.f / Z;    // conf = max w
    }
}

// ---------------------------------------------------------------------------
extern "C" void kernel_launch(void* const* d_in, const int* in_sizes, int n_in,
                              void* d_out, int out_size, void* d_ws, size_t ws_size,
                              hipStream_t stream)
{
    const float* phi_cur = (const float*)d_in[0];
    const float* phi_rnd = (const float*)d_in[1];
    const float* P_cur   = (const float*)d_in[2];
    const float* P_rnd   = (const float*)d_in[3];
    const float* Wq      = (const float*)d_in[4];
    const float* Wk      = (const float*)d_in[5];
    const float* Wv      = (const float*)d_in[6];
    const float* bv      = (const float*)d_in[7];
    const float* gm      = (const float*)d_in[8];
    float* out = (float*)d_out;

    float* q_ws = (float*)d_ws;                      // B*HW*CMID floats
    float* k_ws = q_ws + (size_t)B * HW * CMID;      // B*HW*CMID floats

    proj_kernel<<<dim3(HW / 64, B, 2), 256, 0, stream>>>(
        phi_cur, phi_rnd, Wq, Wk, q_ws, k_ws);

    corr_kernel<<<dim3(B * HW / 4), 256, 0, stream>>>(
        q_ws, k_ws, P_cur, P_rnd, Wv, bv, gm, out);
}

// Round 2
// 369.784 us; speedup vs baseline: 1.2867x; 1.2867x over previous
//
#include <hip/hip_runtime.h>
#include <math.h>

// Problem constants (B, Cin, Cmid, H, W) = (2, 256, 128, 112, 112), R=3
constexpr int B    = 2;
constexpr int CIN  = 256;
constexpr int CMID = 128;
constexpr int H    = 112;
constexpr int W    = 112;
constexpr int HW   = H * W;        // 12544
constexpr int RAD  = 3;
constexpr int KS   = 7;
constexpr int DD   = 49;

// ---------------------------------------------------------------------------
// Kernel 1: q = l2norm(Wq @ phi_cur), k = l2norm(Wk @ phi_rnd)
// Output layout: pixel-major  qk[(b*HW + p)*CMID + c]
// grid (HW/64, B, 2), block 256.  Wave wvu handles channels [32*wvu, +32) for
// 64 pixels (lane = pixel).  W addresses are made PROVABLY wave-uniform via
// readfirstlane so the compiler can emit s_load (SMEM pipe) and feed FMAs
// straight from SGPRs; float4 W reads as fallback vectorization.
// ---------------------------------------------------------------------------
__global__ __launch_bounds__(256) void proj_kernel(
    const float* __restrict__ phi_cur, const float* __restrict__ phi_rnd,
    const float* __restrict__ Wq, const float* __restrict__ Wk,
    float* __restrict__ q_ws, float* __restrict__ k_ws)
{
    const int lane = threadIdx.x & 63;
    const int wvu  = __builtin_amdgcn_readfirstlane(threadIdx.x >> 6); // uniform!
    const int px   = blockIdx.x * 64 + lane;      // pixel in [0,HW)
    const int b    = blockIdx.y;
    const int t    = blockIdx.z;                  // 0 -> q, 1 -> k

    const float* __restrict__ phi = t ? phi_rnd : phi_cur;
    const float* __restrict__ Wm  = t ? Wk : Wq;
    float* __restrict__ outp      = t ? k_ws : q_ws;

    const float* pb = phi + (size_t)b * CIN * HW + px;

    float acc[32];
#pragma unroll
    for (int j = 0; j < 32; ++j) acc[j] = 0.f;

    for (int c0 = 0; c0 < CIN; c0 += 32) {
        float pv[32];
#pragma unroll
        for (int cc = 0; cc < 32; ++cc)
            pv[cc] = pb[(size_t)(c0 + cc) * HW];   // coalesced across lanes
#pragma unroll
        for (int j = 0; j < 32; ++j) {
            const float4* wr = (const float4*)(Wm + (size_t)(wvu * 32 + j) * CIN + c0);
#pragma unroll
            for (int q4 = 0; q4 < 8; ++q4) {
                const float4 wq = wr[q4];          // uniform addr -> s_load
                acc[j] = fmaf(wq.x, pv[q4 * 4 + 0], acc[j]);
                acc[j] = fmaf(wq.y, pv[q4 * 4 + 1], acc[j]);
                acc[j] = fmaf(wq.z, pv[q4 * 4 + 2], acc[j]);
                acc[j] = fmaf(wq.w, pv[q4 * 4 + 3], acc[j]);
            }
        }
    }

    // L2 norm across all 128 channels of this pixel (4 wave-partials)
    float ss = 0.f;
#pragma unroll
    for (int j = 0; j < 32; ++j) ss = fmaf(acc[j], acc[j], ss);

    __shared__ float red[4][64];
    red[wvu][lane] = ss;
    __syncthreads();
    const float tot = red[0][lane] + red[1][lane] + red[2][lane] + red[3][lane];
    const float inv = 1.f / fmaxf(sqrtf(tot), 1e-12f);

    float* op = outp + ((size_t)(b * HW + px)) * CMID + wvu * 32;
#pragma unroll
    for (int j = 0; j < 32; j += 4) {
        float4 v = make_float4(acc[j] * inv, acc[j + 1] * inv,
                               acc[j + 2] * inv, acc[j + 3] * inv);
        *(float4*)(op + j) = v;
    }
}

// ---------------------------------------------------------------------------
// Kernel 2: fused correlation + Wv matmul + geometry + softmax + moments.
// One wave per pixel.  Phase 1 (lane = channel-pair): for each of 49 offsets,
// COALESCED float2 k load, 2 FMAs, DPP butterfly (xor 1/2/4/8) to 16-lane
// group sums, 4 partials stashed in LDS.  Phase 2 (lane = offset d): Wv row
// held in registers, logits, in-wave softmax, moments.
// OOB offsets contribute corr=0 / Pr=0 but stay in the softmax (zero padding).
// ---------------------------------------------------------------------------
__global__ __launch_bounds__(256) void corr_kernel(
    const float* __restrict__ q_ws, const float* __restrict__ k_ws,
    const float* __restrict__ P_cur, const float* __restrict__ P_rnd,
    const float* __restrict__ Wvm, const float* __restrict__ bv,
    const float* __restrict__ gamma_p, float* __restrict__ out)
{
    __shared__ float wv_lds[DD * DD];   // staged coalesced, read per-row below
    __shared__ float cs[4][DD][4];      // per-wave 16-lane-group partials
    __shared__ float csum[4][DD];       // per-wave full correlation vector

    for (int i = threadIdx.x; i < DD * DD; i += 256) wv_lds[i] = Wvm[i];

    const int lane = threadIdx.x & 63;
    const int wvq  = __builtin_amdgcn_readfirstlane(threadIdx.x >> 6);
    const int pg   = blockIdx.x * 4 + wvq;  // pixel among B*HW (uniform/wave)
    const int b    = pg / HW;
    const int p    = pg % HW;
    const int h    = p / W;
    const int w    = p % W;
    const float gamma = gamma_p[0];

    // this lane's 2 channels of q (channels 2*lane, 2*lane+1)
    const float2 qv = ((const float2*)(q_ws + (size_t)pg * CMID))[lane];

    __syncthreads();   // wv_lds ready

    const int ld = (lane < DD) ? lane : 0;
    float wrow[DD];    // Wv row for offset d = lane  (registers)
#pragma unroll
    for (int e = 0; e < DD; ++e) wrow[e] = wv_lds[ld * DD + e];
    const float bvv = bv[ld];

    const float2* kb = (const float2*)k_ws + (size_t)b * HW * (CMID / 2);

    // ---- phase 1: correlation, lane = channel-pair, coalesced gathers ----
#pragma unroll
    for (int d = 0; d < DD; ++d) {
        const int dy = d / KS - RAD, dx = d % KS - RAD;
        const int hn = h + dy, wn = w + dx;          // wave-uniform
        float partial = 0.f;
        if (hn >= 0 && hn < H && wn >= 0 && wn < W) {
            const float2 kv = kb[(size_t)(hn * W + wn) * (CMID / 2) + lane];
            partial = fmaf(qv.x, kv.x, qv.y * kv.y);
        }
        partial += __shfl_xor(partial, 1, 64);       // DPP-cheap butterflies
        partial += __shfl_xor(partial, 2, 64);
        partial += __shfl_xor(partial, 4, 64);
        partial += __shfl_xor(partial, 8, 64);
        if ((lane & 15) == 0) cs[wvq][d][lane >> 4] = partial;
    }
    __syncthreads();
    if (lane < DD) {
        const float4 t4 = *(const float4*)cs[wvq][lane];
        csum[wvq][lane] = (t4.x + t4.y) + (t4.z + t4.w);
    }
    __syncthreads();

    // ---- phase 2: geometry + logits, lane = offset d ----
    const int dy = lane / KS - RAD;
    const int dx = lane % KS - RAD;
    const int hn = h + dy, wn = w + dx;
    const bool valid = (lane < DD);
    const bool inb = valid && (hn >= 0) && (hn < H) && (wn >= 0) && (wn < W);

    const float* pc = P_cur + (size_t)b * 3 * HW + p;
    const float cx = pc[0], cy = pc[HW], cz = pc[2 * HW];   // broadcast
    float rx = 0.f, ry = 0.f, rz = 0.f;
    if (inb) {
        const float* pr = P_rnd + (size_t)b * 3 * HW + hn * W + wn;
        rx = pr[0]; ry = pr[HW]; rz = pr[2 * HW];
    }
    const float dpx = cx - rx, dpy = cy - ry, dpz = cz - rz;
    const float dist = sqrtf(fmaxf(dpx * dpx + dpy * dpy + dpz * dpz, 1e-12f));

    float logit = -INFINITY;
    if (valid) {
        float v = bvv;
#pragma unroll
        for (int e = 0; e < DD; ++e)
            v = fmaf(wrow[e], csum[wvq][e], v);      // csum: LDS broadcast
        logit = v + gamma * (-dist - 0.5f * fabsf(dpz));
    }

    // in-wave softmax over 49 active lanes
    float lmax = logit;
#pragma unroll
    for (int off = 32; off; off >>= 1)
        lmax = fmaxf(lmax, __shfl_xor(lmax, off, 64));
    const float e1 = valid ? __expf(logit - lmax) : 0.f;
    float Z = e1;
#pragma unroll
    for (int off = 32; off; off >>= 1)
        Z += __shfl_xor(Z, off, 64);
    const float wgt = e1 / Z;

    float dus = wgt * (float)dx;
    float dvs = wgt * (float)dy;
#pragma unroll
    for (int off = 32; off; off >>= 1) {
        dus += __shfl_xor(dus, off, 64);
        dvs += __shfl_xor(dvs, off, 64);
    }

    if (lane == 0) {
        out[pg]                      = dus;        // du
        out[(size_t)B * HW + pg]     = dvs;        // dv
        out[2 * (size_t)B * HW + pg] = 1.f / Z;    // conf = max w = 1/Z
    }
}

// ---------------------------------------------------------------------------
extern "C" void kernel_launch(void* const* d_in, const int* in_sizes, int n_in,
                              void* d_out, int out_size, void* d_ws, size_t ws_size,
                              hipStream_t stream)
{
    const float* phi_cur = (const float*)d_in[0];
    const float* phi_rnd = (const float*)d_in[1];
    const float* P_cur   = (const float*)d_in[2];
    const float* P_rnd   = (const float*)d_in[3];
    const float* Wq      = (const float*)d_in[4];
    const float* Wk      = (const float*)d_in[5];
    const float* Wv      = (const float*)d_in[6];
    const float* bv      = (const float*)d_in[7];
    const float* gm      = (const float*)d_in[8];
    float* out = (float*)d_out;

    float* q_ws = (float*)d_ws;                      // B*HW*CMID floats
    float* k_ws = q_ws + (size_t)B * HW * CMID;      // B*HW*CMID floats

    proj_kernel<<<dim3(HW / 64, B, 2), 256, 0, stream>>>(
        phi_cur, phi_rnd, Wq, Wk, q_ws, k_ws);

    corr_kernel<<<dim3(B * HW / 4), 256, 0, stream>>>(
        q_ws, k_ws, P_cur, P_rnd, Wv, bv, gm, out);
}

// Round 3
// 219.276 us; speedup vs baseline: 2.1698x; 1.6864x over previous
//
#include <hip/hip_runtime.h>
#include <math.h>

// Problem constants (B, Cin, Cmid, H, W) = (2, 256, 128, 112, 112), R=3
constexpr int B    = 2;
constexpr int CIN  = 256;
constexpr int CMID = 128;
constexpr int H    = 112;
constexpr int W    = 112;
constexpr int HW   = H * W;        // 12544
constexpr int NPIX = B * HW;       // 25088
constexpr int RAD  = 3;
constexpr int KS   = 7;
constexpr int DD   = 49;

typedef __attribute__((ext_vector_type(8))) short  short8;   // 8 bf16 (4 VGPR)
typedef __attribute__((ext_vector_type(4))) float  float4v;  // MFMA C/D

__device__ __forceinline__ unsigned short f2bf(float f) {   // RNE fp32->bf16
    unsigned u = __float_as_uint(f);
    u += 0x7FFFu + ((u >> 16) & 1u);
    return (unsigned short)(u >> 16);
}
__device__ __forceinline__ unsigned pkbf(float a, float b) {
    return (unsigned)f2bf(a) | ((unsigned)f2bf(b) << 16);
}
__device__ __forceinline__ float bflo(unsigned u) { return __uint_as_float(u << 16); }
__device__ __forceinline__ float bfhi(unsigned u) { return __uint_as_float(u & 0xFFFF0000u); }

// ---------------------------------------------------------------------------
// Kernel 0: convert Wq, Wk fp32 -> bf16 (one-time, tiny)
// ---------------------------------------------------------------------------
__global__ __launch_bounds__(256) void convert_w(
    const float* __restrict__ Wq, const float* __restrict__ Wk,
    unsigned short* __restrict__ wqb, unsigned short* __restrict__ wkb)
{
    const int i  = blockIdx.x * 256 + threadIdx.x;   // float4 index
    const int n4 = (CMID * CIN) / 4;                 // 8192 per matrix
    const float4 v = (i < n4) ? ((const float4*)Wq)[i] : ((const float4*)Wk)[i - n4];
    uint2 r;
    r.x = pkbf(v.x, v.y);
    r.y = pkbf(v.z, v.w);
    if (i < n4) ((uint2*)wqb)[i] = r;
    else        ((uint2*)wkb)[i - n4] = r;
}

// ---------------------------------------------------------------------------
// Kernel 1: q = l2norm(Wq @ phi_cur), k = l2norm(Wk @ phi_rnd)  via bf16 MFMA.
// D[o][p] = sum_c W[o][c] * phi[c][p]:  A = W (M=128 outch), B = phi (N=pixel).
// Wave computes 16 pixels x all 128 outputs (8 o-tiles of 16x16x32 MFMA).
// C/D mapping (m89-verified): col = lane&15 = pixel, row = quad*4+reg = outch.
// Per-pixel l2norm: lane partial + shfl_xor(16,32). Output bf16 pixel-major.
// ---------------------------------------------------------------------------
__global__ __launch_bounds__(256) void proj_mfma(
    const float* __restrict__ phi_cur, const float* __restrict__ phi_rnd,
    const unsigned short* __restrict__ wq_bf, const unsigned short* __restrict__ wk_bf,
    unsigned short* __restrict__ q_ws, unsigned short* __restrict__ k_ws)
{
    const int lane = threadIdx.x & 63;
    const int wv   = __builtin_amdgcn_readfirstlane(threadIdx.x >> 6);
    const int t    = blockIdx.y;                    // 0 -> q, 1 -> k

    const float* __restrict__ phi          = t ? phi_rnd : phi_cur;
    const unsigned short* __restrict__ Wbf = t ? wk_bf : wq_bf;
    unsigned short* __restrict__ outp      = t ? k_ws : q_ws;

    const int pgb  = blockIdx.x * 64 + wv * 16;     // wave's pixel base (global)
    const int b    = pgb / HW;
    const int pim  = pgb % HW;                      // 16-aligned, no b-crossing
    const int m    = lane & 15;
    const int quad = lane >> 4;

    const float* pb = phi + (size_t)b * CIN * HW + (pim + m);

    float4v acc[8];
#pragma unroll
    for (int ot = 0; ot < 8; ++ot) acc[ot] = (float4v)0.f;

#pragma unroll
    for (int ks = 0; ks < 8; ++ks) {
        const int k0 = ks * 32;
        float pv[8];
#pragma unroll
        for (int j = 0; j < 8; ++j)
            pv[j] = pb[(size_t)(k0 + quad * 8 + j) * HW];   // 64B-line efficient
        union { short8 s; unsigned u[4]; } bu;
#pragma unroll
        for (int j2 = 0; j2 < 4; ++j2)
            bu.u[j2] = pkbf(pv[2 * j2], pv[2 * j2 + 1]);
#pragma unroll
        for (int ot = 0; ot < 8; ++ot) {
            const short8 afrag =
                *(const short8*)(Wbf + ((ot * 16 + m) * CIN + k0 + quad * 8));
            acc[ot] = __builtin_amdgcn_mfma_f32_16x16x32_bf16(afrag, bu.s, acc[ot], 0, 0, 0);
        }
    }

    // per-pixel L2 norm: this lane's 32 values all belong to pixel (pim+m)
    float ss = 0.f;
#pragma unroll
    for (int ot = 0; ot < 8; ++ot) {
        ss = fmaf(acc[ot][0], acc[ot][0], ss);
        ss = fmaf(acc[ot][1], acc[ot][1], ss);
        ss = fmaf(acc[ot][2], acc[ot][2], ss);
        ss = fmaf(acc[ot][3], acc[ot][3], ss);
    }
    ss += __shfl_xor(ss, 16, 64);
    ss += __shfl_xor(ss, 32, 64);
    const float inv = 1.f / fmaxf(sqrtf(ss), 1e-12f);

    unsigned short* op = outp + (size_t)(pgb + m) * CMID;
#pragma unroll
    for (int ot = 0; ot < 8; ++ot) {
        uint2 st;
        st.x = pkbf(acc[ot][0] * inv, acc[ot][1] * inv);
        st.y = pkbf(acc[ot][2] * inv, acc[ot][3] * inv);
        *(uint2*)(op + ot * 16 + quad * 4) = st;
    }
}

// ---------------------------------------------------------------------------
// Kernel 2: correlation + Wv + geometry + softmax + moments.
// Block = 16 consecutive pixels of one row. k-tile (7 rows x 22 cols x 128ch,
// bf16, pixel stride 272B -> ~2-way LDS conflicts only) staged in LDS; OOB
// vectors zero-filled so corr naturally matches zero padding.  4 waves x 4
// pixels each; lane = offset d.  Wv row in VGPRs; corr broadcast via LDS.
// ---------------------------------------------------------------------------
constexpr int TILE = 16;
constexpr int COLS = TILE + 6;      // 22
constexpr int NV   = KS * COLS;     // 154 staged pixel-vectors
constexpr int KSTR = 136;           // shorts per vector in LDS (272 B)

__global__ __launch_bounds__(256) void corr_kernel(
    const unsigned short* __restrict__ q_ws, const unsigned short* __restrict__ k_ws,
    const float* __restrict__ P_cur, const float* __restrict__ P_rnd,
    const float* __restrict__ Wvm, const float* __restrict__ bv,
    const float* __restrict__ gamma_p, float* __restrict__ out)
{
    __shared__ unsigned short kt[NV * KSTR];     // 41,888 B
    __shared__ unsigned short qt[TILE * CMID];   //  4,096 B
    __shared__ float cl[4][52];                  // per-wave corr vec (padded)

    const int tid  = threadIdx.x;
    const int lane = tid & 63;
    const int wv   = __builtin_amdgcn_readfirstlane(tid >> 6);
    const int w0   = blockIdx.x * TILE;
    const int h    = blockIdx.y;
    const int b    = blockIdx.z;

    // ---- stage k-tile (coalesced dwordx4; OOB -> zeros) ----
    const int sub  = tid & 15;
    const int vgrp = tid >> 4;          // 0..15
#pragma unroll
    for (int pass = 0; pass < 10; ++pass) {
        const int vi = pass * 16 + vgrp;
        if (vi < NV) {
            const int rr = vi / COLS;
            const int cc = vi % COLS;
            const int hh = h + rr - RAD;
            const int ww = w0 + cc - RAD;
            uint4 v = make_uint4(0, 0, 0, 0);
            if (hh >= 0 && hh < H && ww >= 0 && ww < W)
                v = *(const uint4*)(k_ws + (size_t)(b * HW + hh * W + ww) * CMID + sub * 8);
            *(uint4*)(kt + vi * KSTR + sub * 8) = v;
        }
    }
    // ---- stage q-tile (16 vectors, one pass) ----
    {
        const uint4 v = *(const uint4*)(q_ws + (size_t)(b * HW + h * W + w0 + vgrp) * CMID + sub * 8);
        *(uint4*)(qt + vgrp * CMID + sub * 8) = v;
    }

    // ---- per-lane constants: Wv row (zero-padded to 52) + bias ----
    const int  ld    = (lane < DD) ? lane : 0;
    const bool valid = (lane < DD);
    float wrow[52];
#pragma unroll
    for (int e = 0; e < DD; ++e) wrow[e] = Wvm[ld * DD + e];
    wrow[49] = wrow[50] = wrow[51] = 0.f;
    const float bvv   = bv[ld];
    const float gamma = gamma_p[0];

    const int dyr = ld / KS;            // 0..6
    const int dxc = ld % KS;
    const int dy  = dyr - RAD;
    const int dx  = dxc - RAD;

    __syncthreads();

    for (int i = 0; i < 4; ++i) {
        const int pl = wv * 4 + i;      // pixel local 0..15
        const int pg = b * HW + h * W + w0 + pl;

        // ---- correlation dot over 128 bf16 channels ----
        const unsigned short* kp = kt + (dyr * COLS + pl + dxc) * KSTR;
        const unsigned short* qp = qt + pl * CMID;
        float corr = 0.f;
#pragma unroll
        for (int c8 = 0; c8 < 16; ++c8) {
            const uint4 kv = *(const uint4*)(kp + c8 * 8);
            const uint4 qv = *(const uint4*)(qp + c8 * 8);   // broadcast read
            corr = fmaf(bflo(qv.x), bflo(kv.x), corr);
            corr = fmaf(bfhi(qv.x), bfhi(kv.x), corr);
            corr = fmaf(bflo(qv.y), bflo(kv.y), corr);
            corr = fmaf(bfhi(qv.y), bfhi(kv.y), corr);
            corr = fmaf(bflo(qv.z), bflo(kv.z), corr);
            corr = fmaf(bfhi(qv.z), bfhi(kv.z), corr);
            corr = fmaf(bflo(qv.w), bflo(kv.w), corr);
            corr = fmaf(bfhi(qv.w), bfhi(kv.w), corr);
        }
        if (lane < 52) cl[wv][lane] = valid ? corr : 0.f;
        __syncthreads();

        // ---- geometry ----
        const int hn = h + dy, wn = w0 + pl + dx;
        const bool inb = valid && hn >= 0 && hn < H && wn >= 0 && wn < W;
        const float* pc = P_cur + (size_t)b * 3 * HW + (h * W + w0 + pl);
        const float cx = pc[0], cy = pc[HW], cz = pc[2 * HW];
        float rx = 0.f, ry = 0.f, rz = 0.f;
        if (inb) {
            const float* pr = P_rnd + (size_t)b * 3 * HW + (hn * W + wn);
            rx = pr[0]; ry = pr[HW]; rz = pr[2 * HW];
        }
        const float dpx = cx - rx, dpy = cy - ry, dpz = cz - rz;
        const float dist = sqrtf(fmaxf(dpx * dpx + dpy * dpy + dpz * dpz, 1e-12f));

        // ---- logits: Wv @ corr (float4 LDS broadcast) + bias + geom ----
        float logit = -INFINITY;
        if (valid) {
            float v = bvv;
#pragma unroll
            for (int e4 = 0; e4 < 13; ++e4) {
                const float4 c4 = *(const float4*)&cl[wv][e4 * 4];
                v = fmaf(wrow[e4 * 4 + 0], c4.x, v);
                v = fmaf(wrow[e4 * 4 + 1], c4.y, v);
                v = fmaf(wrow[e4 * 4 + 2], c4.z, v);
                v = fmaf(wrow[e4 * 4 + 3], c4.w, v);
            }
            logit = v + gamma * (-dist - 0.5f * fabsf(dpz));
        }

        // ---- in-wave softmax over 49 active lanes ----
        float lmax = logit;
#pragma unroll
        for (int off = 32; off; off >>= 1)
            lmax = fmaxf(lmax, __shfl_xor(lmax, off, 64));
        const float e1 = valid ? __expf(logit - lmax) : 0.f;
        float Z = e1;
#pragma unroll
        for (int off = 32; off; off >>= 1)
            Z += __shfl_xor(Z, off, 64);
        const float wgt = e1 / Z;

        float dus = wgt * (float)dx;
        float dvs = wgt * (float)dy;
#pragma unroll
        for (int off = 32; off; off >>= 1) {
            dus += __shfl_xor(dus, off, 64);
            dvs += __shfl_xor(dvs, off, 64);
        }

        if (lane == 0) {
            out[pg]            = dus;
            out[NPIX + pg]     = dvs;
            out[2 * NPIX + pg] = 1.f / Z;   // conf = max w
        }
        __syncthreads();
    }
}

// ---------------------------------------------------------------------------
extern "C" void kernel_launch(void* const* d_in, const int* in_sizes, int n_in,
                              void* d_out, int out_size, void* d_ws, size_t ws_size,
                              hipStream_t stream)
{
    const float* phi_cur = (const float*)d_in[0];
    const float* phi_rnd = (const float*)d_in[1];
    const float* P_cur   = (const float*)d_in[2];
    const float* P_rnd   = (const float*)d_in[3];
    const float* Wq      = (const float*)d_in[4];
    const float* Wk      = (const float*)d_in[5];
    const float* Wv      = (const float*)d_in[6];
    const float* bv      = (const float*)d_in[7];
    const float* gm      = (const float*)d_in[8];
    float* out = (float*)d_out;

    unsigned short* ws   = (unsigned short*)d_ws;
    unsigned short* q_ws = ws;                                  // NPIX*CMID bf16
    unsigned short* k_ws = q_ws + (size_t)NPIX * CMID;          // NPIX*CMID bf16
    unsigned short* wqb  = k_ws + (size_t)NPIX * CMID;          // CMID*CIN bf16
    unsigned short* wkb  = wqb + (size_t)CMID * CIN;

    convert_w<<<dim3(2 * CMID * CIN / 4 / 256), 256, 0, stream>>>(Wq, Wk, wqb, wkb);

    proj_mfma<<<dim3(NPIX / 64, 2), 256, 0, stream>>>(
        phi_cur, phi_rnd, wqb, wkb, q_ws, k_ws);

    corr_kernel<<<dim3(W / TILE, H, B), 256, 0, stream>>>(
        q_ws, k_ws, P_cur, P_rnd, Wv, bv, gm, out);
}

// Round 5
// 143.006 us; speedup vs baseline: 3.3271x; 1.5333x over previous
//
#include <hip/hip_runtime.h>
#include <math.h>

// Problem constants (B, Cin, Cmid, H, W) = (2, 256, 128, 112, 112), R=3
constexpr int B    = 2;
constexpr int CIN  = 256;
constexpr int CMID = 128;
constexpr int H    = 112;
constexpr int W    = 112;
constexpr int HW   = H * W;        // 12544
constexpr int NPIX = B * HW;       // 25088
constexpr int RAD  = 3;
constexpr int KS   = 7;
constexpr int DD   = 49;

typedef __attribute__((ext_vector_type(8))) short  short8;   // 8 bf16 (4 VGPR)
typedef __attribute__((ext_vector_type(4))) float  float4v;  // MFMA C/D

__device__ __forceinline__ unsigned short f2bf(float f) {   // RNE fp32->bf16
    unsigned u = __float_as_uint(f);
    u += 0x7FFFu + ((u >> 16) & 1u);
    return (unsigned short)(u >> 16);
}
__device__ __forceinline__ unsigned pkbf(float a, float b) {
    return (unsigned)f2bf(a) | ((unsigned)f2bf(b) << 16);
}

// ---------------------------------------------------------------------------
// Kernel 0: convert Wq, Wk fp32 -> bf16 (one-time, tiny)
// ---------------------------------------------------------------------------
__global__ __launch_bounds__(256) void convert_w(
    const float* __restrict__ Wq, const float* __restrict__ Wk,
    unsigned short* __restrict__ wqb, unsigned short* __restrict__ wkb)
{
    const int i  = blockIdx.x * 256 + threadIdx.x;   // float4 index
    const int n4 = (CMID * CIN) / 4;                 // 8192 per matrix
    const float4 v = (i < n4) ? ((const float4*)Wq)[i] : ((const float4*)Wk)[i - n4];
    uint2 r;
    r.x = pkbf(v.x, v.y);
    r.y = pkbf(v.z, v.w);
    if (i < n4) ((uint2*)wqb)[i] = r;
    else        ((uint2*)wkb)[i - n4] = r;
}

// ---------------------------------------------------------------------------
// Kernel 1: q = l2norm(Wq @ phi_cur), k = l2norm(Wk @ phi_rnd)  via bf16 MFMA.
// Block = 64 pixels, all 128 outputs.  phi tile staged in LDS with COALESCED
// float4 channel-row loads, transposed during write (packed bf16 ch-pairs,
// b32 writes) into pixel-major rows.
// ROW STRIDE = 264 shorts (528 B): holds all 256 channels (round-4 bug was
// stride 136 < 256 -> row overlap + reads past pt into uninit LDS -> NaN).
// 264/2 = 132 dwords = 4 mod 32 -> frag ds_read_b128 is 2-way (free, m136).
// Wave w owns out-channels [32w,32w+32): A-frags (W rows) preloaded into
// registers (16 b128 global, L2-hot); K-loop = 8 x (4 B-frag ds_reads + 8
// MFMA).  Cross-wave l2norm via LDS.  Output bf16 pixel-major.
// ---------------------------------------------------------------------------
constexpr int PSTR = 264;           // shorts per pixel row in pt

__global__ __launch_bounds__(256) void proj_mfma(
    const float* __restrict__ phi_cur, const float* __restrict__ phi_rnd,
    const unsigned short* __restrict__ wq_bf, const unsigned short* __restrict__ wk_bf,
    unsigned short* __restrict__ q_ws, unsigned short* __restrict__ k_ws)
{
    __shared__ unsigned short pt[64 * PSTR];  // 33,792 B  pixel-major bf16
    __shared__ float red[4][64];

    const int tid  = threadIdx.x;
    const int lane = tid & 63;
    const int wv   = __builtin_amdgcn_readfirstlane(tid >> 6);
    const int t    = blockIdx.y;                    // 0 -> q, 1 -> k

    const float* __restrict__ phi          = t ? phi_rnd : phi_cur;
    const unsigned short* __restrict__ Wbf = t ? wk_bf : wq_bf;
    unsigned short* __restrict__ outp      = t ? k_ws : q_ws;

    const int pgb = blockIdx.x * 64;                // 64-aligned, no b crossing
    const int b   = pgb / HW;
    const int pim = pgb % HW;
    const float* pbase = phi + (size_t)b * CIN * HW + pim;

    // ---- stage phi tile: 8 passes; thread -> (channel-pair, pixel-quad) ----
#pragma unroll
    for (int pass = 0; pass < 8; ++pass) {
        const int idx = pass * 256 + tid;
        const int cp  = idx >> 4;          // channel pair 0..127
        const int pq  = idx & 15;          // pixel quad  0..15
        const int c0  = cp * 2;
        const float4 va = *(const float4*)(pbase + (size_t)c0 * HW + pq * 4);
        const float4 vb = *(const float4*)(pbase + (size_t)(c0 + 1) * HW + pq * 4);
        *(unsigned*)(pt + (pq * 4 + 0) * PSTR + c0) = pkbf(va.x, vb.x);
        *(unsigned*)(pt + (pq * 4 + 1) * PSTR + c0) = pkbf(va.y, vb.y);
        *(unsigned*)(pt + (pq * 4 + 2) * PSTR + c0) = pkbf(va.z, vb.z);
        *(unsigned*)(pt + (pq * 4 + 3) * PSTR + c0) = pkbf(va.w, vb.w);
    }

    // ---- A-frags: this wave's 32 W rows, held in registers (L2-hot) ----
    const int m = lane & 15, quad = lane >> 4;
    short8 af[2][8];
#pragma unroll
    for (int ot = 0; ot < 2; ++ot)
#pragma unroll
        for (int kc = 0; kc < 8; ++kc)
            af[ot][kc] = *(const short8*)(Wbf +
                (size_t)(wv * 32 + ot * 16 + m) * CIN + kc * 32 + quad * 8);

    __syncthreads();

    // ---- MFMA: 2 out-tiles x 4 pixel-tiles x K=256 ----
    float4v acc[2][4];
#pragma unroll
    for (int ot = 0; ot < 2; ++ot)
#pragma unroll
        for (int nt = 0; nt < 4; ++nt) acc[ot][nt] = (float4v)0.f;

#pragma unroll
    for (int kc = 0; kc < 8; ++kc) {
        short8 bf[4];
#pragma unroll
        for (int nt = 0; nt < 4; ++nt)
            bf[nt] = *(const short8*)(pt + (nt * 16 + m) * PSTR + kc * 32 + quad * 8);
#pragma unroll
        for (int ot = 0; ot < 2; ++ot)
#pragma unroll
            for (int nt = 0; nt < 4; ++nt)
                acc[ot][nt] = __builtin_amdgcn_mfma_f32_16x16x32_bf16(
                    af[ot][kc], bf[nt], acc[ot][nt], 0, 0, 0);
    }

    // ---- per-pixel L2 norm: C layout col=lane&15=pixel, row=quad*4+reg=och
    // lane partial (8 och values per nt) -> quad-reduce -> cross-wave LDS ----
#pragma unroll
    for (int nt = 0; nt < 4; ++nt) {
        float ss = 0.f;
#pragma unroll
        for (int ot = 0; ot < 2; ++ot)
#pragma unroll
            for (int r = 0; r < 4; ++r)
                ss = fmaf(acc[ot][nt][r], acc[ot][nt][r], ss);
        ss += __shfl_xor(ss, 16, 64);
        ss += __shfl_xor(ss, 32, 64);
        if (quad == 0) red[wv][nt * 16 + m] = ss;
    }
    __syncthreads();

    float inv[4];
#pragma unroll
    for (int nt = 0; nt < 4; ++nt) {
        const int px = nt * 16 + m;
        const float tot = red[0][px] + red[1][px] + red[2][px] + red[3][px];
        inv[nt] = 1.f / fmaxf(sqrtf(tot), 1e-12f);
    }

    // ---- store bf16 pixel-major ----
#pragma unroll
    for (int nt = 0; nt < 4; ++nt)
#pragma unroll
        for (int ot = 0; ot < 2; ++ot) {
            uint2 st;
            st.x = pkbf(acc[ot][nt][0] * inv[nt], acc[ot][nt][1] * inv[nt]);
            st.y = pkbf(acc[ot][nt][2] * inv[nt], acc[ot][nt][3] * inv[nt]);
            *(uint2*)(outp + (size_t)(pgb + nt * 16 + m) * CMID
                      + wv * 32 + ot * 16 + quad * 4) = st;
        }
}

// ---------------------------------------------------------------------------
// Kernel 2: correlation via MFMA band-GEMM + Wv + geometry + softmax.
// Block = 16 pixels of one row.  Phase A: stage k-tile (7x22 pixel-vectors,
// bf16, stride 136 shorts) + q-tile in LDS (coalesced uint4, OOB -> zeros).
// Phase B: for each of 14 (row r, n-tile) groups (round-robin over 4 waves):
// Q(16x128) x Krow^T(128x16|6) via 4 chained 16x16x32 MFMA; band-extract
// D[p][cc] with off = cc - p in [0,6] -> cs[p][r*7+off] (masked b32 writes).
// Phase C (lane = offset d): Wv row in VGPRs, geometry, in-wave softmax,
// moments.  2 barriers per block total.
// ---------------------------------------------------------------------------
constexpr int TILE = 16;
constexpr int COLS = TILE + 6;      // 22
constexpr int NV   = KS * COLS;     // 154 staged pixel-vectors
constexpr int KSTR = 136;           // shorts per vector in LDS (272 B)

__global__ __launch_bounds__(256) void corr_kernel(
    const unsigned short* __restrict__ q_ws, const unsigned short* __restrict__ k_ws,
    const float* __restrict__ P_cur, const float* __restrict__ P_rnd,
    const float* __restrict__ Wvm, const float* __restrict__ bv,
    const float* __restrict__ gamma_p, float* __restrict__ out)
{
    __shared__ unsigned short kt[NV * KSTR];     // 41,888 B
    __shared__ unsigned short qt[TILE * KSTR];   //  4,352 B
    __shared__ float cs[TILE][52];               //  3,328 B corr vectors

    const int tid  = threadIdx.x;
    const int lane = tid & 63;
    const int wv   = __builtin_amdgcn_readfirstlane(tid >> 6);
    const int w0   = blockIdx.x * TILE;
    const int h    = blockIdx.y;
    const int b    = blockIdx.z;

    // ---- phase A: stage k-tile + q-tile (coalesced dwordx4; OOB zeros) ----
    const int sub  = tid & 15;
    const int vgrp = tid >> 4;          // 0..15
#pragma unroll
    for (int pass = 0; pass < 10; ++pass) {
        const int vi = pass * 16 + vgrp;
        if (vi < NV) {
            const int rr = vi / COLS;
            const int cc = vi % COLS;
            const int hh = h + rr - RAD;
            const int ww = w0 + cc - RAD;
            uint4 v = make_uint4(0, 0, 0, 0);
            if (hh >= 0 && hh < H && ww >= 0 && ww < W)
                v = *(const uint4*)(k_ws + (size_t)(b * HW + hh * W + ww) * CMID + sub * 8);
            *(uint4*)(kt + vi * KSTR + sub * 8) = v;
        }
    }
    {
        const uint4 v = *(const uint4*)(q_ws + (size_t)(b * HW + h * W + w0 + vgrp) * CMID + sub * 8);
        *(uint4*)(qt + vgrp * KSTR + sub * 8) = v;
    }

    // ---- per-lane constants for phase C (loads overlap staging) ----
    const int  ld    = (lane < DD) ? lane : 0;
    const bool valid = (lane < DD);
    float wrow[52];
#pragma unroll
    for (int e = 0; e < DD; ++e) wrow[e] = Wvm[ld * DD + e];
    wrow[49] = wrow[50] = wrow[51] = 0.f;
    const float bvv   = bv[ld];
    const float gamma = gamma_p[0];

    __syncthreads();

    // zero the cs padding (cols 49..51) so phase C's 0*pad stays 0
    if (tid < TILE * 3)
        cs[tid / 3][49 + tid % 3] = 0.f;

    // ---- phase B: MFMA band-GEMM ----
    const int m = lane & 15, quad = lane >> 4;
    for (int g = wv; g < 14; g += 4) {
        const int r  = g >> 1;
        const int nt = g & 1;
        const int vi = min(r * COLS + nt * 16 + m, NV - 1);  // clamp OOB cols
        float4v acc = (float4v)0.f;
#pragma unroll
        for (int kc = 0; kc < 4; ++kc) {
            const short8 afrag = *(const short8*)(qt + m * KSTR + kc * 32 + quad * 8);
            const short8 bfrag = *(const short8*)(kt + vi * KSTR + kc * 32 + quad * 8);
            acc = __builtin_amdgcn_mfma_f32_16x16x32_bf16(afrag, bfrag, acc, 0, 0, 0);
        }
        // band extract: D row = pixel = quad*4+reg, col cc = nt*16 + m
#pragma unroll
        for (int reg = 0; reg < 4; ++reg) {
            const int p   = quad * 4 + reg;
            const int off = nt * 16 + m - p;     // dx + RAD
            if (off >= 0 && off <= 6)
                cs[p][r * 7 + off] = acc[reg];
        }
    }
    __syncthreads();

    // ---- phase C: geometry + logits + softmax + moments (lane = d) ----
    const int dy = ld / KS - RAD;
    const int dx = ld % KS - RAD;

    for (int i = 0; i < 4; ++i) {
        const int pl = wv * 4 + i;      // pixel local 0..15
        const int pg = b * HW + h * W + w0 + pl;

        const int hn = h + dy, wn = w0 + pl + dx;
        const bool inb = valid && hn >= 0 && hn < H && wn >= 0 && wn < W;
        const float* pc = P_cur + (size_t)b * 3 * HW + (h * W + w0 + pl);
        const float cx = pc[0], cy = pc[HW], cz = pc[2 * HW];
        float rx = 0.f, ry = 0.f, rz = 0.f;
        if (inb) {
            const float* pr = P_rnd + (size_t)b * 3 * HW + (hn * W + wn);
            rx = pr[0]; ry = pr[HW]; rz = pr[2 * HW];
        }
        const float dpx = cx - rx, dpy = cy - ry, dpz = cz - rz;
        const float dist = sqrtf(fmaxf(dpx * dpx + dpy * dpy + dpz * dpz, 1e-12f));

        float logit = -INFINITY;
        if (valid) {
            float v = bvv;
#pragma unroll
            for (int e4 = 0; e4 < 13; ++e4) {
                const float4 c4 = *(const float4*)&cs[pl][e4 * 4];
                v = fmaf(wrow[e4 * 4 + 0], c4.x, v);
                v = fmaf(wrow[e4 * 4 + 1], c4.y, v);
                v = fmaf(wrow[e4 * 4 + 2], c4.z, v);
                v = fmaf(wrow[e4 * 4 + 3], c4.w, v);
            }
            logit = v + gamma * (-dist - 0.5f * fabsf(dpz));
        }

        float lmax = logit;
#pragma unroll
        for (int off = 32; off; off >>= 1)
            lmax = fmaxf(lmax, __shfl_xor(lmax, off, 64));
        const float e1 = valid ? __expf(logit - lmax) : 0.f;
        float Z = e1;
#pragma unroll
        for (int off = 32; off; off >>= 1)
            Z += __shfl_xor(Z, off, 64);
        const float wgt = e1 / Z;

        float dus = wgt * (float)dx;
        float dvs = wgt * (float)dy;
#pragma unroll
        for (int off = 32; off; off >>= 1) {
            dus += __shfl_xor(dus, off, 64);
            dvs += __shfl_xor(dvs, off, 64);
        }

        if (lane == 0) {
            out[pg]            = dus;
            out[NPIX + pg]     = dvs;
            out[2 * NPIX + pg] = 1.f / Z;   // conf = max w
        }
    }
}

// ---------------------------------------------------------------------------
extern "C" void kernel_launch(void* const* d_in, const int* in_sizes, int n_in,
                              void* d_out, int out_size, void* d_ws, size_t ws_size,
                              hipStream_t stream)
{
    const float* phi_cur = (const float*)d_in[0];
    const float* phi_rnd = (const float*)d_in[1];
    const float* P_cur   = (const float*)d_in[2];
    const float* P_rnd   = (const float*)d_in[3];
    const float* Wq      = (const float*)d_in[4];
    const float* Wk      = (const float*)d_in[5];
    const float* Wv      = (const float*)d_in[6];
    const float* bv      = (const float*)d_in[7];
    const float* gm      = (const float*)d_in[8];
    float* out = (float*)d_out;

    unsigned short* ws   = (unsigned short*)d_ws;
    unsigned short* q_ws = ws;                                  // NPIX*CMID bf16
    unsigned short* k_ws = q_ws + (size_t)NPIX * CMID;          // NPIX*CMID bf16
    unsigned short* wqb  = k_ws + (size_t)NPIX * CMID;          // CMID*CIN bf16
    unsigned short* wkb  = wqb + (size_t)CMID * CIN;

    convert_w<<<dim3(2 * CMID * CIN / 4 / 256), 256, 0, stream>>>(Wq, Wk, wqb, wkb);

    proj_mfma<<<dim3(NPIX / 64, 2), 256, 0, stream>>>(
        phi_cur, phi_rnd, wqb, wkb, q_ws, k_ws);

    corr_kernel<<<dim3(W / TILE, H, B), 256, 0, stream>>>(
        q_ws, k_ws, P_cur, P_rnd, Wv, bv, gm, out);
}